// Round 1
// baseline (18639.334 us; speedup 1.0000x reference)
//
#include <hip/hip_runtime.h>
#include <math.h>
#include <stdint.h>

// Problem: BiLSTMModel  (S=4096 words, L=16 chars, E=256, H=512, HID=512, T=50)
// Phases:
//   1) char-LSTM (batch 4096, 16 steps, hidden 256)  -> word_emb[4096][256]
//   2) BiLSTM layer0 over 4096-length sequence, batch 1, hidden 512
//   3) BiLSTM layer1 (input 1024)
//   4) fc1 (tanh) + fc2 -> out[4096][50]
// Sequential scans use 64 WGs/direction; h_t exchanged via tagged 8B words
// ({fp32,tag}) with relaxed agent-scope atomics (1 LLC RT per step).

#define NPOS 4096
#define GDIM 2048   // 4*H

__device__ __forceinline__ float sigf(float x) { return 1.0f / (1.0f + __expf(-x)); }

// ---------------- build transposed concat char weight: Wt[k][g], k<256: cW_ih, else cW_hh
__global__ __launch_bounds__(256) void build_wt_kernel(
    const float* __restrict__ cWih, const float* __restrict__ cWhh,
    float* __restrict__ Wt)
{
  __shared__ float tile[64][65];
  const int k0 = blockIdx.x * 64;       // 0..448
  const int g0 = blockIdx.y * 64;       // 0..960
  const float* src = (k0 < 256) ? cWih : cWhh;
  const int sk0 = k0 & 255;
  for (int i = threadIdx.x; i < 64 * 64; i += 256) {
    int r = i >> 6, cc = i & 63;
    tile[r][cc] = src[(size_t)(g0 + r) * 256 + sk0 + cc];
  }
  __syncthreads();
  for (int i = threadIdx.x; i < 64 * 64; i += 256) {
    int kk = i >> 6, gg = i & 63;
    Wt[(size_t)(k0 + kk) * 1024 + g0 + gg] = tile[gg][kk];
  }
}

// ---------------- char LSTM: 256 blocks x 16 words, thread = channel (0..255)
__global__ __launch_bounds__(256) void char_lstm_kernel(
    const int* __restrict__ chars, const int* __restrict__ lens,
    const float* __restrict__ table, const float* __restrict__ Wt,
    const float* __restrict__ cb, float* __restrict__ word_emb)
{
  __shared__ float u[16][512];     // [word][k]  k<256: emb, k>=256: h
  __shared__ float wt[8][1024];    // staged weight k-slice
  __shared__ int sidx[16];
  const int tid = threadIdx.x;
  const int ch = tid;              // channel 0..255
  const int w0 = blockIdx.x * 16;
  if (tid < 16) { int l = lens[w0 + tid]; sidx[tid] = (l < 1 ? 1 : l) - 1; }
  float c[16], acc0[16], acc1[16], acc2[16], acc3[16];
  #pragma unroll
  for (int w = 0; w < 16; ++w) { u[w][256 + ch] = 0.f; c[w] = 0.f; }
  const float cb0 = cb[ch], cb1 = cb[256 + ch], cb2 = cb[512 + ch], cb3 = cb[768 + ch];

  for (int t = 0; t < 16; ++t) {
    // stage embeddings for this step (coalesced row loads)
    for (int w = 0; w < 16; ++w) {
      int cid = chars[(w0 + w) * 16 + t];
      u[w][ch] = table[(size_t)cid * 256 + ch];
    }
    #pragma unroll
    for (int w = 0; w < 16; ++w) { acc0[w] = cb0; acc1[w] = cb1; acc2[w] = cb2; acc3[w] = cb3; }
    for (int k0 = 0; k0 < 512; k0 += 8) {
      #pragma unroll
      for (int r = 0; r < 8; ++r)
        ((float4*)&wt[r][0])[tid] = ((const float4*)(Wt + (size_t)(k0 + r) * 1024))[tid];
      __syncthreads();
      #pragma unroll
      for (int kk = 0; kk < 8; ++kk) {
        const float wv0 = wt[kk][ch], wv1 = wt[kk][256 + ch];
        const float wv2 = wt[kk][512 + ch], wv3 = wt[kk][768 + ch];
        #pragma unroll
        for (int w = 0; w < 16; ++w) {
          const float uv = u[w][k0 + kk];   // broadcast read
          acc0[w] = fmaf(wv0, uv, acc0[w]);
          acc1[w] = fmaf(wv1, uv, acc1[w]);
          acc2[w] = fmaf(wv2, uv, acc2[w]);
          acc3[w] = fmaf(wv3, uv, acc3[w]);
        }
      }
      __syncthreads();
    }
    #pragma unroll
    for (int w = 0; w < 16; ++w) {
      float iv = sigf(acc0[w]), fv = sigf(acc1[w]);
      float gv = tanhf(acc2[w]), ov = sigf(acc3[w]);
      c[w] = fv * c[w] + iv * gv;
      float h = ov * tanhf(c[w]);
      u[w][256 + ch] = h;
      if (t == sidx[w]) word_emb[(size_t)(w0 + w) * 256 + ch] = h;
    }
  }
}

// ---------------- generic fp32 GEMM: C[M][N] = act(A[M][K] @ B[N][K]^T + bias[N])
// SPLIT=1: A is two [M][512] fp32 arrays (k<512 -> A, k>=512 -> A2).  ACT=1: tanh.
template <int SPLIT, int ACT>
__global__ __launch_bounds__(256) void gemm_kernel(
    const float* __restrict__ A, const float* __restrict__ A2,
    const float* __restrict__ B, const float* __restrict__ bias,
    float* __restrict__ C, int M, int N, int K)
{
  __shared__ float At[8][132];
  __shared__ float Bt[8][132];
  const int tid = threadIdx.x;
  const int bm0 = blockIdx.x * 128, bn0 = blockIdx.y * 128;
  float acc[8][8];
  #pragma unroll
  for (int i = 0; i < 8; ++i)
    #pragma unroll
    for (int j = 0; j < 8; ++j) acc[i][j] = 0.f;
  const int sr = tid >> 1;           // tile row 0..127
  const int sk = (tid & 1) * 4;      // k sub-offset
  const int tm = (tid >> 4) * 8, tn = (tid & 15) * 8;
  for (int k0 = 0; k0 < K; k0 += 8) {
    const int kg = k0 + sk;
    float4 av;
    if (SPLIT) {
      const float* srcp = (kg < 512) ? A : A2;
      av = *(const float4*)(srcp + (size_t)(bm0 + sr) * 512 + (kg & 511));
    } else {
      av = *(const float4*)(A + (size_t)(bm0 + sr) * K + kg);
    }
    float4 bv = {0.f, 0.f, 0.f, 0.f};
    if (bn0 + sr < N) bv = *(const float4*)(B + (size_t)(bn0 + sr) * K + kg);
    At[sk + 0][sr] = av.x; At[sk + 1][sr] = av.y; At[sk + 2][sr] = av.z; At[sk + 3][sr] = av.w;
    Bt[sk + 0][sr] = bv.x; Bt[sk + 1][sr] = bv.y; Bt[sk + 2][sr] = bv.z; Bt[sk + 3][sr] = bv.w;
    __syncthreads();
    #pragma unroll
    for (int kk = 0; kk < 8; ++kk) {
      float a[8], b[8];
      *(float4*)&a[0] = *(const float4*)&At[kk][tm];
      *(float4*)&a[4] = *(const float4*)&At[kk][tm + 4];
      *(float4*)&b[0] = *(const float4*)&Bt[kk][tn];
      *(float4*)&b[4] = *(const float4*)&Bt[kk][tn + 4];
      #pragma unroll
      for (int i = 0; i < 8; ++i)
        #pragma unroll
        for (int j = 0; j < 8; ++j) acc[i][j] = fmaf(a[i], b[j], acc[i][j]);
    }
    __syncthreads();
  }
  #pragma unroll
  for (int i = 0; i < 8; ++i) {
    const int m = bm0 + tm + i;
    float* crow = C + (size_t)m * N;
    #pragma unroll
    for (int j = 0; j < 8; ++j) {
      const int n = bn0 + tn + j;
      if (n < N) {
        float v = acc[i][j] + bias[n];
        if (ACT) v = tanhf(v);
        crow[n] = v;
      }
    }
  }
}

// ---------------- persistent bidirectional scan (one layer, both directions)
// grid = 128 blocks: dir = bid>>6, wg = bid&63. WG owns hidden units [wg*8, wg*8+8).
// thread = (row8 = tid>>3 in 0..31, klane = tid&7). Gate row R = (row8>>3)*512 + wg*8 + (row8&7).
// h exchanged as tagged 8B words: lo32 = fp32 h, hi32 = step+1.
__global__ __launch_bounds__(256) void scan_kernel(
    const float* __restrict__ Xf, const float* __restrict__ Xb,
    const float* __restrict__ Whf, const float* __restrict__ Whb,
    unsigned long long* __restrict__ Tf, unsigned long long* __restrict__ Tb,
    float* __restrict__ Hf, float* __restrict__ Hb)
{
  __shared__ float lds_h[528];   // padded: logical j stored at j + (j>>5)
  __shared__ float gsc[32];
  const int tid = threadIdx.x;
  const int dir = blockIdx.x >> 6;
  const int wg = blockIdx.x & 63;
  const float* X = dir ? Xb : Xf;
  const float* Wh = dir ? Whb : Whf;
  unsigned long long* T = dir ? Tb : Tf;
  float* Hd = dir ? Hb : Hf;
  const int row8 = tid >> 3, klane = tid & 7;
  const int R = (row8 >> 3) * 512 + wg * 8 + (row8 & 7);
  // weights into registers: 64 contiguous k per thread
  float wreg[64];
  {
    const float* wrow = Wh + (size_t)R * 512 + klane * 64;
    #pragma unroll
    for (int i = 0; i < 16; ++i) {
      float4 v = ((const float4*)wrow)[i];
      wreg[4 * i] = v.x; wreg[4 * i + 1] = v.y; wreg[4 * i + 2] = v.z; wreg[4 * i + 3] = v.w;
    }
  }
  for (int i = tid; i < 528; i += 256) lds_h[i] = 0.f;
  float creg = 0.f;
  const int off0 = klane * 64;
  const int l0 = off0 + (off0 >> 5);
  const int off1 = off0 + 32;
  const int l1 = off1 + (off1 >> 5);
  const int j0 = 2 * tid;
  const int la = j0 + (j0 >> 5);
  __syncthreads();

  for (int s = 0; s < NPOS; ++s) {
    const int p = dir ? (NPOS - 1 - s) : s;
    const float xv = X[(size_t)p * GDIM + R];
    if (s > 0) {
      const int pprev = dir ? (NPOS - s) : (s - 1);
      unsigned long long* srcp = T + (size_t)pprev * 512 + j0;
      const unsigned int tg = (unsigned int)s;
      unsigned long long v0, v1;
      do { v0 = __hip_atomic_load(srcp, __ATOMIC_RELAXED, __HIP_MEMORY_SCOPE_AGENT); }
      while ((unsigned int)(v0 >> 32) != tg);
      do { v1 = __hip_atomic_load(srcp + 1, __ATOMIC_RELAXED, __HIP_MEMORY_SCOPE_AGENT); }
      while ((unsigned int)(v1 >> 32) != tg);
      lds_h[la] = __uint_as_float((unsigned int)v0);
      lds_h[la + 1] = __uint_as_float((unsigned int)v1);
    }
    __syncthreads();
    float sum = (klane == 0) ? xv : 0.f;
    #pragma unroll
    for (int i = 0; i < 32; ++i) sum = fmaf(wreg[i], lds_h[l0 + i], sum);
    #pragma unroll
    for (int i = 0; i < 32; ++i) sum = fmaf(wreg[32 + i], lds_h[l1 + i], sum);
    sum += __shfl_xor(sum, 1);
    sum += __shfl_xor(sum, 2);
    sum += __shfl_xor(sum, 4);
    if (klane == 0) gsc[row8] = sum;
    __syncthreads();
    if (tid < 8) {
      float iv = sigf(gsc[tid]), fv = sigf(gsc[8 + tid]);
      float gv = tanhf(gsc[16 + tid]), ov = sigf(gsc[24 + tid]);
      creg = fv * creg + iv * gv;
      float h = ov * tanhf(creg);
      const int j = wg * 8 + tid;
      unsigned long long pack =
          ((unsigned long long)(unsigned int)(s + 1) << 32) | (unsigned long long)__float_as_uint(h);
      __hip_atomic_store(&T[(size_t)p * 512 + j], pack, __ATOMIC_RELAXED, __HIP_MEMORY_SCOPE_AGENT);
      Hd[(size_t)p * 512 + j] = h;
    }
  }
}

extern "C" void kernel_launch(void* const* d_in, const int* in_sizes, int n_in,
                              void* d_out, int out_size, void* d_ws, size_t ws_size,
                              hipStream_t stream) {
  const int* chars = (const int*)d_in[0];
  const int* lens = (const int*)d_in[1];
  const float* table = (const float*)d_in[2];
  const float* cWih = (const float*)d_in[3];
  const float* cWhh = (const float*)d_in[4];
  const float* cb = (const float*)d_in[5];
  const float* Wih0 = (const float*)d_in[6];   // [2][2048][256]
  const float* Whh0 = (const float*)d_in[7];   // [2][2048][512]
  const float* b0 = (const float*)d_in[8];     // [2][2048]
  const float* Wih1 = (const float*)d_in[9];   // [2][2048][1024]
  const float* Whh1 = (const float*)d_in[10];  // [2][2048][512]
  const float* b1 = (const float*)d_in[11];    // [2][2048]
  const float* fc1w = (const float*)d_in[12];  // [512][1024]
  const float* fc1b = (const float*)d_in[13];
  const float* fc2w = (const float*)d_in[14];  // [50][512]
  const float* fc2b = (const float*)d_in[15];
  float* out = (float*)d_out;

  char* ws = (char*)d_ws;
  size_t off = 0;
  auto alloc = [&](size_t bytes) -> void* {
    void* p = ws + off;
    off += (bytes + 255) & ~(size_t)255;
    return p;
  };
  float* word_emb = (float*)alloc((size_t)4096 * 256 * 4);
  float* X0f = (float*)alloc((size_t)4096 * 2048 * 4);   // reused as X1f
  float* X0b = (float*)alloc((size_t)4096 * 2048 * 4);   // reused as X1b
  float* H0f = (float*)alloc((size_t)4096 * 512 * 4);
  float* H0b = (float*)alloc((size_t)4096 * 512 * 4);
  float* H1f = (float*)alloc((size_t)4096 * 512 * 4);
  float* H1b = (float*)alloc((size_t)4096 * 512 * 4);
  float* fc1out = (float*)alloc((size_t)4096 * 512 * 4);
  float* Wt = (float*)alloc((size_t)512 * 1024 * 4);
  unsigned long long* Tall = (unsigned long long*)alloc((size_t)4 * 4096 * 512 * 8);
  unsigned long long* T0f = Tall;
  unsigned long long* T0b = Tall + (size_t)4096 * 512;
  unsigned long long* T1f = Tall + (size_t)2 * 4096 * 512;
  unsigned long long* T1b = Tall + (size_t)3 * 4096 * 512;
  if (off > ws_size) return;  // workspace too small: fail loudly (output stays poisoned)

  // 1) clear tag buffers (inside graph -> every replay re-synchronizes honestly)
  hipMemsetAsync(Tall, 0, (size_t)4 * 4096 * 512 * 8, stream);

  // 2) char weights transpose + char LSTM
  build_wt_kernel<<<dim3(8, 16), 256, 0, stream>>>(cWih, cWhh, Wt);
  char_lstm_kernel<<<256, 256, 0, stream>>>(chars, lens, table, Wt, cb, word_emb);

  // 3) layer0 x2h GEMMs + scan
  gemm_kernel<0, 0><<<dim3(32, 16), 256, 0, stream>>>(
      word_emb, nullptr, Wih0, b0, X0f, 4096, 2048, 256);
  gemm_kernel<0, 0><<<dim3(32, 16), 256, 0, stream>>>(
      word_emb, nullptr, Wih0 + (size_t)2048 * 256, b0 + 2048, X0b, 4096, 2048, 256);
  scan_kernel<<<128, 256, 0, stream>>>(X0f, X0b, Whh0, Whh0 + (size_t)2048 * 512,
                                       T0f, T0b, H0f, H0b);

  // 4) layer1 x2h GEMMs (input = concat(H0f,H0b)) + scan
  gemm_kernel<1, 0><<<dim3(32, 16), 256, 0, stream>>>(
      H0f, H0b, Wih1, b1, X0f, 4096, 2048, 1024);
  gemm_kernel<1, 0><<<dim3(32, 16), 256, 0, stream>>>(
      H0f, H0b, Wih1 + (size_t)2048 * 1024, b1 + 2048, X0b, 4096, 2048, 1024);
  scan_kernel<<<128, 256, 0, stream>>>(X0f, X0b, Whh1, Whh1 + (size_t)2048 * 512,
                                       T1f, T1b, H1f, H1b);

  // 5) fc1 (tanh) + fc2
  gemm_kernel<1, 1><<<dim3(32, 4), 256, 0, stream>>>(
      H1f, H1b, fc1w, fc1b, fc1out, 4096, 512, 1024);
  gemm_kernel<0, 0><<<dim3(32, 1), 256, 0, stream>>>(
      fc1out, nullptr, fc2w, fc2b, out, 4096, 50, 512);
}